// Round 1
// baseline (223.186 us; speedup 1.0000x reference)
//
#include <hip/hip_runtime.h>
#include <hip/hip_bf16.h>
#include <stdint.h>

// Attention: b=4, n=4097, d=128, h=8, dh=16, scale = d**-0.5.
// Interface (R5): fp32 in, fp32 out, ws >= 33.6MB usable.
// R14: (1) attn row-sum moved from chained fdot2 (VALU pipe, the 64%-busy
// bottleneck) to an all-ones-A MFMA accumulator (layout-agnostic, MFMA pipe
// had 2x slack); launch_bounds relaxed 8->4 waves/EU for the +16 VGPR.
// (2) qkv_mfma/out_mfma were 257 blocks = 1 wave/SIMD latency-bound; now
// MT blocks x 4 waves splitting the nt-range (4x latency hiding, same work).
// (3) x16 staging pass removed; qkv converts fp32->f16 inline.

#define BB 4
#define NN 4097
#define NNP 4112
#define DD 128
#define HH 8
#define DH 16
#define BH (BB*HH)    // 32
#define ROWS (BB*NN)  // 16388
#define MT  1025      // ceil(ROWS/16) m-tiles

typedef _Float16 h4 __attribute__((ext_vector_type(4)));
typedef _Float16 h8 __attribute__((ext_vector_type(8)));
typedef __fp16   fp16v2 __attribute__((ext_vector_type(2)));
typedef float    f4 __attribute__((ext_vector_type(4)));

#define QSCALE (0.08838834764831845f * 1.4426950408889634f)  // 128^-.5 * log2e

#if __has_builtin(__builtin_amdgcn_exp2f)
#define EXP2F(x) __builtin_amdgcn_exp2f(x)
#else
#define EXP2F(x) exp2f(x)
#endif

union H4u { h4 v; fp16v2 p[2]; };

static __device__ __forceinline__ H4u pack4u(float a, float b, float c, float d) {
    H4u u;
#if __has_builtin(__builtin_amdgcn_cvt_pkrtz)
    u.p[0] = __builtin_amdgcn_cvt_pkrtz(a, b);
    u.p[1] = __builtin_amdgcn_cvt_pkrtz(c, d);
#else
    u.v[0] = (_Float16)a; u.v[1] = (_Float16)b; u.v[2] = (_Float16)c; u.v[3] = (_Float16)d;
#endif
    return u;
}

// ---------------- K0: prep — W_qkv^T (Q-scaled) + W_out^T in f16 -------
__global__ __launch_bounds__(256) void prep(
    const float* __restrict__ Wqkv,
    const float* __restrict__ Wout,
    _Float16* __restrict__ WqkvT,   // [384][128], rows 0..127 pre-scaled by QSCALE
    _Float16* __restrict__ WoutT)   // [128][128]
{
    const int id = blockIdx.x*256 + threadIdx.x;
    if (id < 384*128) {
        const int n = id >> 7, k = id & 127;
        const float s = (n < 128) ? QSCALE : 1.0f;
        WqkvT[id] = (_Float16)(Wqkv[k*384 + n] * s);
    } else if (id < 384*128 + 128*128) {
        const int e = id - 384*128;
        const int n = e >> 7, k = e & 127;
        WoutT[e] = (_Float16)(Wout[k*128 + n]);
    }
}

// ---------------- K1: qkv = x @ WqkvT^T + b, via MFMA ----------------
// D[m=row(quad*4+reg)][n=col(l16)]; A[m=l16][k=quad*4+j]; B[k=quad*4+j][n=l16].
// One block per m-tile; its 4 waves split the 24 nt across 6-nt chunks
// (R14: was 1 wave/SIMD on the whole nt-range -> latency-bound).
__global__ __launch_bounds__(256) void qkv_mfma(
    const float* __restrict__ x,
    const _Float16* __restrict__ WqkvT,
    const float* __restrict__ bqkv,
    _Float16* __restrict__ Qh,    // [BH][NNP][16]
    _Float16* __restrict__ Kh,    // [BH][NNP][16]
    _Float16* __restrict__ Vh)    // [BH][NNP][16] row-major
{
    const int wid  = blockIdx.x;                  // m-tile
    const int wave = threadIdx.x >> 6;            // 0..3 -> nt chunk
    const int lane = threadIdx.x & 63;
    const int quad = lane >> 4, l16 = lane & 15;

    const int arow = wid*16 + l16;
    const int arc  = (arow < ROWS) ? arow : (ROWS - 1);
    const float* xr = x + (size_t)arc*DD;
    h4 af[8];
    #pragma unroll
    for (int kk = 0; kk < 8; ++kk) {
        const float4 t = *(const float4*)(xr + kk*16 + quad*4);
        af[kk] = pack4u(t.x, t.y, t.z, t.w).v;
    }

    const int r0 = wid*16 + quad*4;
    const int nt0 = wave*6;

    for (int nt = nt0; nt < nt0 + 6; nt += 2) {
        const float b0 = bqkv[nt*16 + l16]      * ((nt   < 8) ? QSCALE : 1.0f);
        const float b1 = bqkv[nt*16 + 16 + l16] * ((nt+1 < 8) ? QSCALE : 1.0f);
        f4 a0 = {b0,b0,b0,b0}, a1 = {b1,b1,b1,b1};
        #pragma unroll
        for (int kk = 0; kk < 8; ++kk) {
            const h4 bf0 = *(const h4*)(WqkvT + (size_t)(nt*16     + l16)*DD + kk*16 + quad*4);
            const h4 bf1 = *(const h4*)(WqkvT + (size_t)(nt*16 + 16 + l16)*DD + kk*16 + quad*4);
            a0 = __builtin_amdgcn_mfma_f32_16x16x16f16(af[kk], bf0, a0, 0, 0, 0);
            a1 = __builtin_amdgcn_mfma_f32_16x16x16f16(af[kk], bf1, a1, 0, 0, 0);
        }
        #pragma unroll
        for (int u = 0; u < 2; ++u) {
            const int ntc = nt + u;
            const int which = ntc >> 3, head = ntc & 7;
            _Float16* base = (which == 0) ? Qh : ((which == 1) ? Kh : Vh);
            const f4 av = u ? a1 : a0;
            #pragma unroll
            for (int r = 0; r < 4; ++r) {
                const int row = r0 + r;
                if (row < ROWS) {
                    const int bidx = row / NN;
                    const int nrow = row - bidx*NN;
                    base[((size_t)(bidx*HH + head)*NNP + nrow)*DH + l16] = (_Float16)av[r];
                }
            }
        }
    }
}

// ---------------- K1b: Vh [bh][n][16] -> Vt [bh][16][NNP] (R10-proven) ---------
__global__ __launch_bounds__(256) void vt_transpose(
    const _Float16* __restrict__ Vh,
    _Float16* __restrict__ Vt)
{
    __shared__ _Float16 tile[128][DH + 2];
    const int tl  = blockIdx.x;              // 0..32
    const int bh  = blockIdx.y;              // 0..31
    const int tid = threadIdx.x;             // 0..255
    const int n0  = tl * 128;
    const int rem = (n0 + 128 <= NNP) ? 128 : (NNP - n0);

    {
        const int r  = tid >> 1;
        const int i8 = (tid & 1) * 8;
        const int rc = (r < rem) ? r : (rem - 1);
        const h8 v = *(const h8*)(Vh + ((size_t)bh*NNP + n0 + rc)*DH + i8);
        #pragma unroll
        for (int j = 0; j < 8; ++j) tile[r][i8 + j] = v[j];
    }
    __syncthreads();
    {
        const int i    = tid >> 4;      // 0..15
        const int nseg = tid & 15;      // 0..15
        if (nseg * 8 < rem) {
            h8 v;
            #pragma unroll
            for (int j = 0; j < 8; ++j) v[j] = tile[nseg*8 + j][i];
            *(h8*)(Vt + ((size_t)bh*DH + i)*NNP + n0 + nseg*8) = v;
        }
    }
}

// ---------------- K2: MFMA flash attention ----------------
// R14: row-sum ls via all-ones-A MFMA (replicated row-sum in every acc reg,
// layout-agnostic) instead of 8 chained fdot2/tile on the saturated VALU pipe.
__global__ __launch_bounds__(256, 4) void attn_mfma(
    const _Float16* __restrict__ Qh,
    const _Float16* __restrict__ Kh,
    const _Float16* __restrict__ Vt,
    _Float16* __restrict__ PACC,   // [4][ROWS][DD] per-split normalized out (f16)
    float* __restrict__ PL)        // [4][ROWS][HH] per-split row sums
{
    const int qt   = blockIdx.x;       // 0..16
    const int bh   = blockIdx.y;       // 0..31
    const int sp   = blockIdx.z;       // 0..3
    const int tid  = threadIdx.x;
    const int wave = tid >> 6;
    const int lane = tid & 63;
    const int quad = lane >> 4;
    const int l16  = lane & 15;
    const int bidx = bh >> 3, head = bh & 7;

    const int qbase = qt*256 + wave*64;

    const _Float16* Qb = Qh + (size_t)bh*NNP*DH;
    h4 qf[4];
    #pragma unroll
    for (int g = 0; g < 4; ++g) {
        const int qr = qbase + g*16 + l16;
        const int qc = (qr < NN) ? qr : (NN-1);
        qf[g] = *(const h4*)(Qb + (size_t)qc*DH + quad*4);
    }

    f4 acc[4]  = {{0,0,0,0},{0,0,0,0},{0,0,0,0},{0,0,0,0}};
    f4 lacc[4] = {{0,0,0,0},{0,0,0,0},{0,0,0,0},{0,0,0,0}};
    const h4 ones4 = {(_Float16)1.f, (_Float16)1.f, (_Float16)1.f, (_Float16)1.f};

    const int t0 = sp*64;
    const int t1 = t0 + 64;

    const _Float16* kp = Kh + ((size_t)bh*NNP + (size_t)t0*16 + l16)*DH + quad*4;
    const _Float16* vp = Vt + ((size_t)bh*DH + l16)*NNP + t0*16 + quad*4;

    h4 ak = *(const h4*)kp;
    h4 av = *(const h4*)vp;
    const f4 zero = {0.f,0.f,0.f,0.f};

    for (int tt = t0; tt < t1; ++tt) {
        kp += 16*DH; vp += 16;
        const h4 nak = *(const h4*)kp;   // prefetch (tile <= 256 in-bounds)
        const h4 nav = *(const h4*)vp;
        #pragma unroll
        for (int g = 0; g < 4; ++g) {
            f4 d = __builtin_amdgcn_mfma_f32_16x16x16f16(ak, qf[g], zero, 0, 0, 0);
            const float p0 = EXP2F(d[0]), p1 = EXP2F(d[1]), p2 = EXP2F(d[2]), p3 = EXP2F(d[3]);
            const H4u pb = pack4u(p0, p1, p2, p3);
            lacc[g] = __builtin_amdgcn_mfma_f32_16x16x16f16(ones4, pb.v, lacc[g], 0, 0, 0);
            acc[g]  = __builtin_amdgcn_mfma_f32_16x16x16f16(av,    pb.v, acc[g],  0, 0, 0);
        }
        ak = nak; av = nav;
    }

    if (sp == 3) {   // tile 256: keys 4096..4111; only key 4096 (quad==0, reg 0) valid
        #pragma unroll
        for (int g = 0; g < 4; ++g) {
            f4 d = __builtin_amdgcn_mfma_f32_16x16x16f16(ak, qf[g], zero, 0, 0, 0);
            const float p0 = (quad == 0) ? EXP2F(d[0]) : 0.f;
            const H4u pb = pack4u(p0, 0.f, 0.f, 0.f);
            lacc[g] = __builtin_amdgcn_mfma_f32_16x16x16f16(ones4, pb.v, lacc[g], 0, 0, 0);
            acc[g]  = __builtin_amdgcn_mfma_f32_16x16x16f16(av,    pb.v, acc[g],  0, 0, 0);
        }
    }

    const size_t rb = (size_t)sp*ROWS + (size_t)bidx*NN;
    #pragma unroll
    for (int g = 0; g < 4; ++g) {
        const float l = lacc[g][0];    // row-sum replicated in all regs/quads
        const int qr = qbase + g*16 + l16;
        if (qr < NN) {
            const float inv = 1.0f / l;   // per-split normalize: f16-safe range
            const H4u st = pack4u(acc[g][0]*inv, acc[g][1]*inv, acc[g][2]*inv, acc[g][3]*inv);
            *(h4*)(PACC + (rb + qr)*DD + head*DH + quad*4) = st.v;
            if (quad == 0) PL[(rb + qr)*HH + head] = l;
        }
    }
}

// ---------------- K3: merged-AO @ Wout + b via MFMA ----------------
// A-frag built from 4-split merge (head == kk for each k-tile: exact softmax).
// One block per m-tile; 4 waves split the 8 nt (R14: was 1 wave/SIMD).
__global__ __launch_bounds__(256) void out_mfma(
    const _Float16* __restrict__ PACC,
    const float* __restrict__ PL,
    const _Float16* __restrict__ WoutT,   // [128][128]
    const float* __restrict__ bout,
    float* __restrict__ out)
{
    const int wid  = blockIdx.x;                  // m-tile
    const int wave = threadIdx.x >> 6;            // 0..3 -> nt pair
    const int lane = threadIdx.x & 63;
    const int quad = lane >> 4, l16 = lane & 15;

    const int arow = wid*16 + l16;
    const int arc  = (arow < ROWS) ? arow : (ROWS - 1);

    h4 af[8];
    #pragma unroll
    for (int kk = 0; kk < 8; ++kk) {
        float n0 = 0.f, n1 = 0.f, n2 = 0.f, n3 = 0.f, lsum = 0.f;
        #pragma unroll
        for (int sp = 0; sp < 4; ++sp) {
            const float l = PL[((size_t)sp*ROWS + arc)*HH + kk];   // head == kk
            lsum += l;
            const h4 p = *(const h4*)(PACC + ((size_t)sp*ROWS + arc)*DD + kk*16 + quad*4);
            n0 += l*(float)p[0]; n1 += l*(float)p[1];
            n2 += l*(float)p[2]; n3 += l*(float)p[3];
        }
        const float inv = 1.0f / lsum;
        const H4u u = pack4u(n0*inv, n1*inv, n2*inv, n3*inv);
        af[kk] = u.v;
    }

    const int r0 = wid*16 + quad*4;
    const int nt = wave*2;

    {
        const float b0 = bout[nt*16 + l16];
        const float b1 = bout[nt*16 + 16 + l16];
        f4 a0 = {b0,b0,b0,b0}, a1 = {b1,b1,b1,b1};
        #pragma unroll
        for (int kk = 0; kk < 8; ++kk) {
            const h4 bf0 = *(const h4*)(WoutT + (size_t)(nt*16      + l16)*DD + kk*16 + quad*4);
            const h4 bf1 = *(const h4*)(WoutT + (size_t)(nt*16 + 16 + l16)*DD + kk*16 + quad*4);
            a0 = __builtin_amdgcn_mfma_f32_16x16x16f16(af[kk], bf0, a0, 0, 0, 0);
            a1 = __builtin_amdgcn_mfma_f32_16x16x16f16(af[kk], bf1, a1, 0, 0, 0);
        }
        #pragma unroll
        for (int r = 0; r < 4; ++r) {
            const int row = r0 + r;
            if (row < ROWS) {
                out[(size_t)row*DD + nt*16      + l16] = a0[r];
                out[(size_t)row*DD + nt*16 + 16 + l16] = a1[r];
            }
        }
    }
}

extern "C" void kernel_launch(void* const* d_in, const int* in_sizes, int n_in,
                              void* d_out, int out_size, void* d_ws, size_t ws_size,
                              hipStream_t stream) {
    const float* x    = (const float*)d_in[0];
    const float* Wqkv = (const float*)d_in[1];
    const float* bqkv = (const float*)d_in[2];
    const float* Wout = (const float*)d_in[3];
    const float* bout = (const float*)d_in[4];
    for (int i = 0; i < n_in; ++i) {
        switch (in_sizes[i]) {
            case 2097664: x    = (const float*)d_in[i]; break;
            case 49152:   Wqkv = (const float*)d_in[i]; break;
            case 384:     bqkv = (const float*)d_in[i]; break;
            case 16384:   Wout = (const float*)d_in[i]; break;
            case 128:     bout = (const float*)d_in[i]; break;
            default: break;
        }
    }
    float* out = (float*)d_out;

    const size_t perh = (size_t)BH * NNP * DH;            // 2,105,344 f16
    _Float16* Qh   = (_Float16*)d_ws;                     // 4.21 MB
    _Float16* Kh   = Qh + perh;                           // 4.21 MB
    _Float16* Vt   = Kh + perh;                           // 4.21 MB
    _Float16* Vh   = Vt + perh;                           // 4.21 MB (dead after vt)
    _Float16* PACC = Vh;                                  // [4][ROWS][DD] f16 16.78 MB
    float*    PL    = (float*)(PACC + (size_t)4*ROWS*DD); // 2.1 MB
    _Float16* WqkvT = (_Float16*)(PL + (size_t)4*ROWS*HH);// 96 KB
    _Float16* WoutT = WqkvT + 384*128;                    // 32 KB -> total ~29.6 MB

    const int prep_total = 384*128 + 128*128;

    hipLaunchKernelGGL(prep, dim3((prep_total + 255)/256), dim3(256), 0, stream,
                       Wqkv, Wout, WqkvT, WoutT);
    hipLaunchKernelGGL(qkv_mfma, dim3(MT), dim3(256), 0, stream,
                       x, WqkvT, bqkv, Qh, Kh, Vh);
    hipLaunchKernelGGL(vt_transpose, dim3(33, BH), dim3(256), 0, stream,
                       Vh, Vt);
    hipLaunchKernelGGL(attn_mfma, dim3(17, BH, 4), dim3(256), 0, stream,
                       Qh, Kh, Vt, PACC, PL);
    hipLaunchKernelGGL(out_mfma, dim3(MT), dim3(256), 0, stream,
                       PACC, PL, WoutT, bout, out);
}

// Round 2
// 188.155 us; speedup vs baseline: 1.1862x; 1.1862x over previous
//
#include <hip/hip_runtime.h>
#include <hip/hip_bf16.h>
#include <stdint.h>

// Attention: b=4, n=4097, d=128, h=8, dh=16, scale = d**-0.5.
// Interface (R5): fp32 in, fp32 out, ws >= 33.6MB usable.
// R15: counters proved legacy v_mfma_f32_16x16x16f16 costs ~16.4 cyc
// (R13: 4.46M mfma = 29.8us busy; R14: 6.68M = 45.0us -> linear) vs ~4.85
// for gfx950-native 16x16x32_f16. All GEMM MFMAs moved to K=32:
//  - QK: dh=16 zero-padded to k=32 (Q-operand quads 2,3 = 0 -> exact).
//  - PV: kept K=16 (K=32 would need cross-quad P repack on the VALU pipe,
//    which is the bottleneck — R14 lesson: don't trade into the hot pipe).
//  - qkv/out projections: K=128 as 4 native K=32 steps (was 8 legacy).
// R14's ones-MFMA ls reverted to fdot2 (added 50% work on a 16-cyc pipe).
// out_mfma back to 1 wave/m-tile (R14's nt-split 4x'd the PACC merge reads).

#define BB 4
#define NN 4097
#define NNP 4112
#define DD 128
#define HH 8
#define DH 16
#define BH (BB*HH)    // 32
#define ROWS (BB*NN)  // 16388
#define MT  1025      // ceil(ROWS/16) m-tiles

typedef _Float16 h4 __attribute__((ext_vector_type(4)));
typedef _Float16 h8 __attribute__((ext_vector_type(8)));
typedef __fp16   fp16v2 __attribute__((ext_vector_type(2)));
typedef float    f4 __attribute__((ext_vector_type(4)));

#define QSCALE (0.08838834764831845f * 1.4426950408889634f)  // 128^-.5 * log2e

#if __has_builtin(__builtin_amdgcn_exp2f)
#define EXP2F(x) __builtin_amdgcn_exp2f(x)
#else
#define EXP2F(x) exp2f(x)
#endif

union H4u { h4 v; fp16v2 p[2]; };
union H8u { h8 v; fp16v2 p[4]; };

static __device__ __forceinline__ H4u pack4u(float a, float b, float c, float d) {
    H4u u;
#if __has_builtin(__builtin_amdgcn_cvt_pkrtz)
    u.p[0] = __builtin_amdgcn_cvt_pkrtz(a, b);
    u.p[1] = __builtin_amdgcn_cvt_pkrtz(c, d);
#else
    u.v[0] = (_Float16)a; u.v[1] = (_Float16)b; u.v[2] = (_Float16)c; u.v[3] = (_Float16)d;
#endif
    return u;
}

// ---------------- K0: prep — x->f16, W_qkv^T (Q-scaled) + W_out^T in f16 -------
__global__ __launch_bounds__(256) void prep(
    const float* __restrict__ x,
    const float* __restrict__ Wqkv,
    const float* __restrict__ Wout,
    _Float16* __restrict__ x16,     // [ROWS][128]
    _Float16* __restrict__ WqkvT,   // [384][128], rows 0..127 pre-scaled by QSCALE
    _Float16* __restrict__ WoutT)   // [128][128]
{
    const int id = blockIdx.x*256 + threadIdx.x;
    const int NX8 = ROWS*DD/8;                  // 262208
    if (id < NX8) {
        const float4* s = (const float4*)(x + (size_t)id*8);
        const float4 a = s[0], b = s[1];
        const H4u u0 = pack4u(a.x, a.y, a.z, a.w);
        const H4u u1 = pack4u(b.x, b.y, b.z, b.w);
        h4* d = (h4*)(x16 + (size_t)id*8);
        d[0] = u0.v; d[1] = u1.v;
    } else if (id < NX8 + 384*128) {
        const int e = id - NX8;
        const int n = e >> 7, k = e & 127;
        const float s = (n < 128) ? QSCALE : 1.0f;
        WqkvT[e] = (_Float16)(Wqkv[k*384 + n] * s);
    } else if (id < NX8 + 384*128 + 128*128) {
        const int e = id - NX8 - 384*128;
        const int n = e >> 7, k = e & 127;
        WoutT[e] = (_Float16)(Wout[k*128 + n]);
    }
}

// ---------------- K1: qkv = x16 @ WqkvT^T + b, via K=32 MFMA ----------------
// D[m=quad*4+reg][n=l16]; A[m=l16][k=quad*8+j]; B[k=quad*8+j][n=l16].
// One block per m-tile; 4 waves split the 24 nt (af re-load is 4x 16B L1 hits).
__global__ __launch_bounds__(256) void qkv_mfma(
    const _Float16* __restrict__ x16,
    const _Float16* __restrict__ WqkvT,
    const float* __restrict__ bqkv,
    _Float16* __restrict__ Qh,    // [BH][NNP][16]
    _Float16* __restrict__ Kh,    // [BH][NNP][16]
    _Float16* __restrict__ Vh)    // [BH][NNP][16] row-major
{
    const int wid  = blockIdx.x;                  // m-tile 0..1024
    const int wave = threadIdx.x >> 6;            // 0..3 -> nt chunk
    const int lane = threadIdx.x & 63;
    const int quad = lane >> 4, l16 = lane & 15;

    const int arow = wid*16 + l16;
    const int arc  = (arow < ROWS) ? arow : (ROWS - 1);
    h8 af[4];
    #pragma unroll
    for (int kk = 0; kk < 4; ++kk)
        af[kk] = *(const h8*)(x16 + (size_t)arc*DD + kk*32 + quad*8);

    const int r0 = wid*16 + quad*4;
    const int nt0 = wave*6;

    for (int nt = nt0; nt < nt0 + 6; nt += 2) {
        const float b0 = bqkv[nt*16 + l16]      * ((nt   < 8) ? QSCALE : 1.0f);
        const float b1 = bqkv[nt*16 + 16 + l16] * ((nt+1 < 8) ? QSCALE : 1.0f);
        f4 a0 = {b0,b0,b0,b0}, a1 = {b1,b1,b1,b1};
        #pragma unroll
        for (int kk = 0; kk < 4; ++kk) {
            const h8 bf0 = *(const h8*)(WqkvT + (size_t)(nt*16      + l16)*DD + kk*32 + quad*8);
            const h8 bf1 = *(const h8*)(WqkvT + (size_t)(nt*16 + 16 + l16)*DD + kk*32 + quad*8);
            a0 = __builtin_amdgcn_mfma_f32_16x16x32_f16(af[kk], bf0, a0, 0, 0, 0);
            a1 = __builtin_amdgcn_mfma_f32_16x16x32_f16(af[kk], bf1, a1, 0, 0, 0);
        }
        #pragma unroll
        for (int u = 0; u < 2; ++u) {
            const int ntc = nt + u;
            const int which = ntc >> 3, head = ntc & 7;
            _Float16* base = (which == 0) ? Qh : ((which == 1) ? Kh : Vh);
            const f4 av = u ? a1 : a0;
            #pragma unroll
            for (int r = 0; r < 4; ++r) {
                const int row = r0 + r;
                if (row < ROWS) {
                    const int bidx = row / NN;
                    const int nrow = row - bidx*NN;
                    base[((size_t)(bidx*HH + head)*NNP + nrow)*DH + l16] = (_Float16)av[r];
                }
            }
        }
    }
}

// ---------------- K1b: Vh [bh][n][16] -> Vt [bh][16][NNP] (R10-proven) ---------
__global__ __launch_bounds__(256) void vt_transpose(
    const _Float16* __restrict__ Vh,
    _Float16* __restrict__ Vt)
{
    __shared__ _Float16 tile[128][DH + 2];
    const int tl  = blockIdx.x;              // 0..32
    const int bh  = blockIdx.y;              // 0..31
    const int tid = threadIdx.x;             // 0..255
    const int n0  = tl * 128;
    const int rem = (n0 + 128 <= NNP) ? 128 : (NNP - n0);

    {
        const int r  = tid >> 1;
        const int i8 = (tid & 1) * 8;
        const int rc = (r < rem) ? r : (rem - 1);
        const h8 v = *(const h8*)(Vh + ((size_t)bh*NNP + n0 + rc)*DH + i8);
        #pragma unroll
        for (int j = 0; j < 8; ++j) tile[r][i8 + j] = v[j];
    }
    __syncthreads();
    {
        const int i    = tid >> 4;      // 0..15
        const int nseg = tid & 15;      // 0..15
        if (nseg * 8 < rem) {
            h8 v;
            #pragma unroll
            for (int j = 0; j < 8; ++j) v[j] = tile[nseg*8 + j][i];
            *(h8*)(Vt + ((size_t)bh*DH + i)*NNP + n0 + nseg*8) = v;
        }
    }
}

// ---------------- K2: MFMA flash attention ----------------
// QK via 16x16x32_f16 with dh zero-padded to 32: qf quads 2,3 are zero
// (exact: 0*finite=0); ak quads 2,3 alias quads 0,1's rows (finite).
// PV stays K=16. ls via fdot2 (R13-proven). 128-thread blocks.
__global__ __launch_bounds__(128, 6) void attn_mfma(
    const _Float16* __restrict__ Qh,
    const _Float16* __restrict__ Kh,
    const _Float16* __restrict__ Vt,
    _Float16* __restrict__ PACC,   // [4][ROWS][DD] per-split normalized out (f16)
    float* __restrict__ PL)        // [4][ROWS][HH] per-split row sums
{
    const int qc2  = blockIdx.x;       // 0..32
    const int bh   = blockIdx.y;       // 0..31
    const int sp   = blockIdx.z;       // 0..3
    const int tid  = threadIdx.x;
    const int wave = tid >> 6;         // 0..1
    const int lane = tid & 63;
    const int quad = lane >> 4;
    const int l16  = lane & 15;
    const int bidx = bh >> 3, head = bh & 7;

    const int qbase = (qc2*2 + wave)*64;

    const _Float16* Qb = Qh + (size_t)bh*NNP*DH;
    h8 qf[4];
    #pragma unroll
    for (int g = 0; g < 4; ++g) {
        h8 t = {0,0,0,0,0,0,0,0};
        if (quad < 2) {
            const int qr = qbase + g*16 + l16;
            const int qc = (qr < NN) ? qr : (NN-1);
            t = *(const h8*)(Qb + (size_t)qc*DH + quad*8);
        }
        qf[g] = t;
    }

    f4 acc[4] = {{0,0,0,0},{0,0,0,0},{0,0,0,0},{0,0,0,0}};
    float ls[4] = {0.f,0.f,0.f,0.f};

    const int t0 = sp*64;
    const int t1 = t0 + 64;

    // K operand: quads 2,3 alias quads 0,1 (multiplied by qf zeros -> 0).
    const _Float16* kp = Kh + ((size_t)bh*NNP + (size_t)t0*16 + l16)*DH + (quad&1)*8;
    const _Float16* vp = Vt + ((size_t)bh*DH + l16)*NNP + t0*16 + quad*4;

    h8 ak = *(const h8*)kp;
    h4 av = *(const h4*)vp;
    const f4 zero = {0.f,0.f,0.f,0.f};
#if __has_builtin(__builtin_amdgcn_fdot2)
    const fp16v2 one2 = {(__fp16)1.0f, (__fp16)1.0f};
#endif

    for (int tt = t0; tt < t1; ++tt) {
        kp += 16*DH; vp += 16;
        const h8 nak = *(const h8*)kp;   // prefetch (tile <= 256 in-bounds)
        const h4 nav = *(const h4*)vp;
        #pragma unroll
        for (int g = 0; g < 4; ++g) {
            f4 d = __builtin_amdgcn_mfma_f32_16x16x32_f16(ak, qf[g], zero, 0, 0, 0);
            const float p0 = EXP2F(d[0]), p1 = EXP2F(d[1]), p2 = EXP2F(d[2]), p3 = EXP2F(d[3]);
            const H4u pb = pack4u(p0, p1, p2, p3);
#if __has_builtin(__builtin_amdgcn_fdot2)
            ls[g] = __builtin_amdgcn_fdot2(pb.p[0], one2,
                     __builtin_amdgcn_fdot2(pb.p[1], one2, ls[g], false), false);
#else
            ls[g] += (p0 + p1) + (p2 + p3);
#endif
            acc[g] = __builtin_amdgcn_mfma_f32_16x16x16f16(av, pb.v, acc[g], 0, 0, 0);
        }
        ak = nak; av = nav;
    }

    if (sp == 3) {   // tile 256: keys 4096..4111; only key 4096 (quad==0, reg 0) valid
        #pragma unroll
        for (int g = 0; g < 4; ++g) {
            f4 d = __builtin_amdgcn_mfma_f32_16x16x32_f16(ak, qf[g], zero, 0, 0, 0);
            const float p0 = (quad == 0) ? EXP2F(d[0]) : 0.f;
            ls[g] += p0;
            const H4u pb = pack4u(p0, 0.f, 0.f, 0.f);
            acc[g] = __builtin_amdgcn_mfma_f32_16x16x16f16(av, pb.v, acc[g], 0, 0, 0);
        }
    }

    const size_t rb = (size_t)sp*ROWS + (size_t)bidx*NN;
    #pragma unroll
    for (int g = 0; g < 4; ++g) {
        float l = ls[g];
        l += __shfl_xor(l, 16);
        l += __shfl_xor(l, 32);
        const int qr = qbase + g*16 + l16;
        if (qr < NN) {
            const float inv = 1.0f / l;   // per-split normalize: f16-safe range
            const H4u st = pack4u(acc[g][0]*inv, acc[g][1]*inv, acc[g][2]*inv, acc[g][3]*inv);
            *(h4*)(PACC + (rb + qr)*DD + head*DH + quad*4) = st.v;
            if (quad == 0) PL[(rb + qr)*HH + head] = l;
        }
    }
}

// ---------------- K3: merged-AO @ Wout + b via K=32 MFMA ----------------
// A-frag from 4-split merge; af8[kk2] spans dims kk2*32+quad*8+j, all within
// head = 2*kk2 + (quad>>1). One wave per m-tile (R13 geometry).
__global__ __launch_bounds__(256) void out_mfma(
    const _Float16* __restrict__ PACC,
    const float* __restrict__ PL,
    const _Float16* __restrict__ WoutT,   // [128][128]
    const float* __restrict__ bout,
    float* __restrict__ out)
{
    const int wid  = blockIdx.x*4 + (threadIdx.x >> 6);   // m-tile
    if (wid >= MT) return;
    const int lane = threadIdx.x & 63;
    const int quad = lane >> 4, l16 = lane & 15;
    const int hq   = quad >> 1;

    const int arow = wid*16 + l16;
    const int arc  = (arow < ROWS) ? arow : (ROWS - 1);

    h8 af[4];
    #pragma unroll
    for (int kk = 0; kk < 4; ++kk) {
        const int head = kk*2 + hq;
        float n0=0.f,n1=0.f,n2=0.f,n3=0.f,n4=0.f,n5=0.f,n6=0.f,n7=0.f,lsum=0.f;
        #pragma unroll
        for (int sp = 0; sp < 4; ++sp) {
            const float l = PL[((size_t)sp*ROWS + arc)*HH + head];
            lsum += l;
            const h8 p = *(const h8*)(PACC + ((size_t)sp*ROWS + arc)*DD + kk*32 + quad*8);
            n0 += l*(float)p[0]; n1 += l*(float)p[1];
            n2 += l*(float)p[2]; n3 += l*(float)p[3];
            n4 += l*(float)p[4]; n5 += l*(float)p[5];
            n6 += l*(float)p[6]; n7 += l*(float)p[7];
        }
        const float inv = 1.0f / lsum;
        H8u u;
#if __has_builtin(__builtin_amdgcn_cvt_pkrtz)
        u.p[0] = __builtin_amdgcn_cvt_pkrtz(n0*inv, n1*inv);
        u.p[1] = __builtin_amdgcn_cvt_pkrtz(n2*inv, n3*inv);
        u.p[2] = __builtin_amdgcn_cvt_pkrtz(n4*inv, n5*inv);
        u.p[3] = __builtin_amdgcn_cvt_pkrtz(n6*inv, n7*inv);
#else
        u.v[0]=(_Float16)(n0*inv); u.v[1]=(_Float16)(n1*inv);
        u.v[2]=(_Float16)(n2*inv); u.v[3]=(_Float16)(n3*inv);
        u.v[4]=(_Float16)(n4*inv); u.v[5]=(_Float16)(n5*inv);
        u.v[6]=(_Float16)(n6*inv); u.v[7]=(_Float16)(n7*inv);
#endif
        af[kk] = u.v;
    }

    const int r0 = wid*16 + quad*4;

    for (int nt = 0; nt < 8; nt += 2) {
        const float b0 = bout[nt*16 + l16];
        const float b1 = bout[nt*16 + 16 + l16];
        f4 a0 = {b0,b0,b0,b0}, a1 = {b1,b1,b1,b1};
        #pragma unroll
        for (int kk = 0; kk < 4; ++kk) {
            const h8 bf0 = *(const h8*)(WoutT + (size_t)(nt*16      + l16)*DD + kk*32 + quad*8);
            const h8 bf1 = *(const h8*)(WoutT + (size_t)(nt*16 + 16 + l16)*DD + kk*32 + quad*8);
            a0 = __builtin_amdgcn_mfma_f32_16x16x32_f16(af[kk], bf0, a0, 0, 0, 0);
            a1 = __builtin_amdgcn_mfma_f32_16x16x32_f16(af[kk], bf1, a1, 0, 0, 0);
        }
        #pragma unroll
        for (int r = 0; r < 4; ++r) {
            const int row = r0 + r;
            if (row < ROWS) {
                out[(size_t)row*DD + nt*16      + l16] = a0[r];
                out[(size_t)row*DD + nt*16 + 16 + l16] = a1[r];
            }
        }
    }
}

extern "C" void kernel_launch(void* const* d_in, const int* in_sizes, int n_in,
                              void* d_out, int out_size, void* d_ws, size_t ws_size,
                              hipStream_t stream) {
    const float* x    = (const float*)d_in[0];
    const float* Wqkv = (const float*)d_in[1];
    const float* bqkv = (const float*)d_in[2];
    const float* Wout = (const float*)d_in[3];
    const float* bout = (const float*)d_in[4];
    for (int i = 0; i < n_in; ++i) {
        switch (in_sizes[i]) {
            case 2097664: x    = (const float*)d_in[i]; break;
            case 49152:   Wqkv = (const float*)d_in[i]; break;
            case 384:     bqkv = (const float*)d_in[i]; break;
            case 16384:   Wout = (const float*)d_in[i]; break;
            case 128:     bout = (const float*)d_in[i]; break;
            default: break;
        }
    }
    float* out = (float*)d_out;

    const size_t perh = (size_t)BH * NNP * DH;            // 2,105,344 f16
    _Float16* Qh   = (_Float16*)d_ws;                     // 4.21 MB
    _Float16* Kh   = Qh + perh;                           // 4.21 MB
    _Float16* Vt   = Kh + perh;                           // 4.21 MB
    _Float16* Vh   = Vt + perh;                           // 4.21 MB (dead after vt)
    _Float16* PACC = Vh;                                  // [4][ROWS][DD] f16 16.78 MB
    _Float16* x16  = Vh + perh;                           // 4.2 MB, inside PACC tail
                                                          // (dead before attn writes PACC)
    float*    PL    = (float*)(PACC + (size_t)4*ROWS*DD); // 2.1 MB
    _Float16* WqkvT = (_Float16*)(PL + (size_t)4*ROWS*HH);// 96 KB
    _Float16* WoutT = WqkvT + 384*128;                    // 32 KB -> total ~31.7 MB

    const int NX8 = ROWS*DD/8;
    const int prep_total = NX8 + 384*128 + 128*128;

    hipLaunchKernelGGL(prep, dim3((prep_total + 255)/256), dim3(256), 0, stream,
                       x, Wqkv, Wout, x16, WqkvT, WoutT);
    hipLaunchKernelGGL(qkv_mfma, dim3(MT), dim3(256), 0, stream,
                       x16, WqkvT, bqkv, Qh, Kh, Vh);
    hipLaunchKernelGGL(vt_transpose, dim3(33, BH), dim3(256), 0, stream,
                       Vh, Vt);
    hipLaunchKernelGGL(attn_mfma, dim3(33, BH, 4), dim3(128), 0, stream,
                       Qh, Kh, Vt, PACC, PL);
    hipLaunchKernelGGL(out_mfma, dim3((MT + 3)/4), dim3(256), 0, stream,
                       PACC, PL, WoutT, bout, out);
}

// Round 3
// 185.330 us; speedup vs baseline: 1.2043x; 1.0152x over previous
//
#include <hip/hip_runtime.h>
#include <hip/hip_bf16.h>
#include <stdint.h>

// Attention: b=4, n=4097, d=128, h=8, dh=16, scale = d**-0.5.
// Interface (R5): fp32 in, fp32 out, ws >= 33.6MB usable.
// R16: calibration from R15 counters: legacy 16x16x16f16 = ~16.5 cyc/SIMD
// (496 FLOP/cyc) vs 16x16x32 = 19.4 cyc (845 FLOP/cyc). K=32 only pays when
// the contraction is >=32 deep -> projections keep K=32; QK (dh=16) reverts
// to K=16 (R15's zero-padded K=32 did 2x FLOPs at 1.18x cycles = strictly
// worse). attn reverted to R13 structure (89.3us) with NSP=2 splits:
// 1088 blocks = single residency round (was 2176 vs ~2048 slots), and
// PACC/PL store traffic halved. out_mfma stays 1 wave/m-tile (R14: nt-split
// redundancy regressed) but hoists ALL loads into unrolled reg arrays with
// launch_bounds(256,1): at 1 wave/SIMD occupancy is moot, MLP is everything.

#define BB 4
#define NN 4097
#define NNP 4112
#define DD 128
#define HH 8
#define DH 16
#define BH (BB*HH)    // 32
#define ROWS (BB*NN)  // 16388
#define MT  1025      // ceil(ROWS/16) m-tiles
#define NSP 2         // attention key-splits

typedef _Float16 h4 __attribute__((ext_vector_type(4)));
typedef _Float16 h8 __attribute__((ext_vector_type(8)));
typedef __fp16   fp16v2 __attribute__((ext_vector_type(2)));
typedef float    f4 __attribute__((ext_vector_type(4)));

#define QSCALE (0.08838834764831845f * 1.4426950408889634f)  // 128^-.5 * log2e

#if __has_builtin(__builtin_amdgcn_exp2f)
#define EXP2F(x) __builtin_amdgcn_exp2f(x)
#else
#define EXP2F(x) exp2f(x)
#endif

union H4u { h4 v; fp16v2 p[2]; };
union H8u { h8 v; fp16v2 p[4]; };

static __device__ __forceinline__ H4u pack4u(float a, float b, float c, float d) {
    H4u u;
#if __has_builtin(__builtin_amdgcn_cvt_pkrtz)
    u.p[0] = __builtin_amdgcn_cvt_pkrtz(a, b);
    u.p[1] = __builtin_amdgcn_cvt_pkrtz(c, d);
#else
    u.v[0] = (_Float16)a; u.v[1] = (_Float16)b; u.v[2] = (_Float16)c; u.v[3] = (_Float16)d;
#endif
    return u;
}

// ---------------- K0: prep — x->f16, W_qkv^T (Q-scaled) + W_out^T in f16 -------
__global__ __launch_bounds__(256) void prep(
    const float* __restrict__ x,
    const float* __restrict__ Wqkv,
    const float* __restrict__ Wout,
    _Float16* __restrict__ x16,     // [ROWS][128]
    _Float16* __restrict__ WqkvT,   // [384][128], rows 0..127 pre-scaled by QSCALE
    _Float16* __restrict__ WoutT)   // [128][128]
{
    const int id = blockIdx.x*256 + threadIdx.x;
    const int NX8 = ROWS*DD/8;                  // 262208
    if (id < NX8) {
        const float4* s = (const float4*)(x + (size_t)id*8);
        const float4 a = s[0], b = s[1];
        const H4u u0 = pack4u(a.x, a.y, a.z, a.w);
        const H4u u1 = pack4u(b.x, b.y, b.z, b.w);
        h4* d = (h4*)(x16 + (size_t)id*8);
        d[0] = u0.v; d[1] = u1.v;
    } else if (id < NX8 + 384*128) {
        const int e = id - NX8;
        const int n = e >> 7, k = e & 127;
        const float s = (n < 128) ? QSCALE : 1.0f;
        WqkvT[e] = (_Float16)(Wqkv[k*384 + n] * s);
    } else if (id < NX8 + 384*128 + 128*128) {
        const int e = id - NX8 - 384*128;
        const int n = e >> 7, k = e & 127;
        WoutT[e] = (_Float16)(Wout[k*128 + n]);
    }
}

// ---------------- K1: qkv = x16 @ WqkvT^T + b, via K=32 MFMA ----------------
// D[m=quad*4+reg][n=l16]; A[m=l16][k=quad*8+j]; B[k=quad*8+j][n=l16].
// One block per m-tile; 4 waves split the 24 nt (af re-load is 4x 16B L1 hits).
__global__ __launch_bounds__(256) void qkv_mfma(
    const _Float16* __restrict__ x16,
    const _Float16* __restrict__ WqkvT,
    const float* __restrict__ bqkv,
    _Float16* __restrict__ Qh,    // [BH][NNP][16]
    _Float16* __restrict__ Kh,    // [BH][NNP][16]
    _Float16* __restrict__ Vh)    // [BH][NNP][16] row-major
{
    const int wid  = blockIdx.x;                  // m-tile 0..1024
    const int wave = threadIdx.x >> 6;            // 0..3 -> nt chunk
    const int lane = threadIdx.x & 63;
    const int quad = lane >> 4, l16 = lane & 15;

    const int arow = wid*16 + l16;
    const int arc  = (arow < ROWS) ? arow : (ROWS - 1);
    h8 af[4];
    #pragma unroll
    for (int kk = 0; kk < 4; ++kk)
        af[kk] = *(const h8*)(x16 + (size_t)arc*DD + kk*32 + quad*8);

    const int r0 = wid*16 + quad*4;
    const int nt0 = wave*6;

    for (int nt = nt0; nt < nt0 + 6; nt += 2) {
        const float b0 = bqkv[nt*16 + l16]      * ((nt   < 8) ? QSCALE : 1.0f);
        const float b1 = bqkv[nt*16 + 16 + l16] * ((nt+1 < 8) ? QSCALE : 1.0f);
        f4 a0 = {b0,b0,b0,b0}, a1 = {b1,b1,b1,b1};
        #pragma unroll
        for (int kk = 0; kk < 4; ++kk) {
            const h8 bf0 = *(const h8*)(WqkvT + (size_t)(nt*16      + l16)*DD + kk*32 + quad*8);
            const h8 bf1 = *(const h8*)(WqkvT + (size_t)(nt*16 + 16 + l16)*DD + kk*32 + quad*8);
            a0 = __builtin_amdgcn_mfma_f32_16x16x32_f16(af[kk], bf0, a0, 0, 0, 0);
            a1 = __builtin_amdgcn_mfma_f32_16x16x32_f16(af[kk], bf1, a1, 0, 0, 0);
        }
        #pragma unroll
        for (int u = 0; u < 2; ++u) {
            const int ntc = nt + u;
            const int which = ntc >> 3, head = ntc & 7;
            _Float16* base = (which == 0) ? Qh : ((which == 1) ? Kh : Vh);
            const f4 av = u ? a1 : a0;
            #pragma unroll
            for (int r = 0; r < 4; ++r) {
                const int row = r0 + r;
                if (row < ROWS) {
                    const int bidx = row / NN;
                    const int nrow = row - bidx*NN;
                    base[((size_t)(bidx*HH + head)*NNP + nrow)*DH + l16] = (_Float16)av[r];
                }
            }
        }
    }
}

// ---------------- K1b: Vh [bh][n][16] -> Vt [bh][16][NNP] (R10-proven) ---------
__global__ __launch_bounds__(256) void vt_transpose(
    const _Float16* __restrict__ Vh,
    _Float16* __restrict__ Vt)
{
    __shared__ _Float16 tile[128][DH + 2];
    const int tl  = blockIdx.x;              // 0..32
    const int bh  = blockIdx.y;              // 0..31
    const int tid = threadIdx.x;             // 0..255
    const int n0  = tl * 128;
    const int rem = (n0 + 128 <= NNP) ? 128 : (NNP - n0);

    {
        const int r  = tid >> 1;
        const int i8 = (tid & 1) * 8;
        const int rc = (r < rem) ? r : (rem - 1);
        const h8 v = *(const h8*)(Vh + ((size_t)bh*NNP + n0 + rc)*DH + i8);
        #pragma unroll
        for (int j = 0; j < 8; ++j) tile[r][i8 + j] = v[j];
    }
    __syncthreads();
    {
        const int i    = tid >> 4;      // 0..15
        const int nseg = tid & 15;      // 0..15
        if (nseg * 8 < rem) {
            h8 v;
            #pragma unroll
            for (int j = 0; j < 8; ++j) v[j] = tile[nseg*8 + j][i];
            *(h8*)(Vt + ((size_t)bh*DH + i)*NNP + n0 + nseg*8) = v;
        }
    }
}

// ---------------- K2: MFMA flash attention (R13 structure, NSP=2) ----------------
__global__ __launch_bounds__(256, 8) void attn_mfma(
    const _Float16* __restrict__ Qh,
    const _Float16* __restrict__ Kh,
    const _Float16* __restrict__ Vt,
    _Float16* __restrict__ PACC,   // [NSP][ROWS][DD] per-split normalized out (f16)
    float* __restrict__ PL)        // [NSP][ROWS][HH] per-split row sums
{
    const int qt   = blockIdx.x;       // 0..16
    const int bh   = blockIdx.y;       // 0..31
    const int sp   = blockIdx.z;       // 0..NSP-1
    const int tid  = threadIdx.x;
    const int wave = tid >> 6;
    const int lane = tid & 63;
    const int quad = lane >> 4;
    const int l16  = lane & 15;
    const int bidx = bh >> 3, head = bh & 7;

    const int qbase = qt*256 + wave*64;

    const _Float16* Qb = Qh + (size_t)bh*NNP*DH;
    h4 qf[4];
    #pragma unroll
    for (int g = 0; g < 4; ++g) {
        const int qr = qbase + g*16 + l16;
        const int qc = (qr < NN) ? qr : (NN-1);
        qf[g] = *(const h4*)(Qb + (size_t)qc*DH + quad*4);
    }

    f4 acc[4] = {{0,0,0,0},{0,0,0,0},{0,0,0,0},{0,0,0,0}};
    float ls[4] = {0.f,0.f,0.f,0.f};

    const int t0 = sp*(4096/NSP/16);
    const int t1 = t0 + (4096/NSP/16);

    const _Float16* kp = Kh + ((size_t)bh*NNP + (size_t)t0*16 + l16)*DH + quad*4;
    const _Float16* vp = Vt + ((size_t)bh*DH + l16)*NNP + t0*16 + quad*4;

    h4 ak = *(const h4*)kp;
    h4 av = *(const h4*)vp;
    const f4 zero = {0.f,0.f,0.f,0.f};
#if __has_builtin(__builtin_amdgcn_fdot2)
    const fp16v2 one2 = {(__fp16)1.0f, (__fp16)1.0f};
#endif

    #pragma unroll 2
    for (int tt = t0; tt < t1; ++tt) {
        kp += 16*DH; vp += 16;
        const h4 nak = *(const h4*)kp;   // prefetch (rows <= NNP stay in-bounds)
        const h4 nav = *(const h4*)vp;
        #pragma unroll
        for (int g = 0; g < 4; ++g) {
            f4 d = __builtin_amdgcn_mfma_f32_16x16x16f16(ak, qf[g], zero, 0, 0, 0);
            const float p0 = EXP2F(d[0]), p1 = EXP2F(d[1]), p2 = EXP2F(d[2]), p3 = EXP2F(d[3]);
            const H4u pb = pack4u(p0, p1, p2, p3);
#if __has_builtin(__builtin_amdgcn_fdot2)
            ls[g] = __builtin_amdgcn_fdot2(pb.p[0], one2,
                     __builtin_amdgcn_fdot2(pb.p[1], one2, ls[g], false), false);
#else
            ls[g] += (p0 + p1) + (p2 + p3);
#endif
            acc[g] = __builtin_amdgcn_mfma_f32_16x16x16f16(av, pb.v, acc[g], 0, 0, 0);
        }
        ak = nak; av = nav;
    }

    if (sp == NSP-1) {   // keys 4096..4111; only key 4096 (quad==0, reg 0) valid
        #pragma unroll
        for (int g = 0; g < 4; ++g) {
            f4 d = __builtin_amdgcn_mfma_f32_16x16x16f16(ak, qf[g], zero, 0, 0, 0);
            const float p0 = (quad == 0) ? EXP2F(d[0]) : 0.f;
            ls[g] += p0;
            const H4u pb = pack4u(p0, 0.f, 0.f, 0.f);
            acc[g] = __builtin_amdgcn_mfma_f32_16x16x16f16(av, pb.v, acc[g], 0, 0, 0);
        }
    }

    const size_t rb = (size_t)sp*ROWS + (size_t)bidx*NN;
    #pragma unroll
    for (int g = 0; g < 4; ++g) {
        float l = ls[g];
        l += __shfl_xor(l, 16);
        l += __shfl_xor(l, 32);
        const int qr = qbase + g*16 + l16;
        if (qr < NN) {
            const float inv = 1.0f / l;   // per-split normalize: f16-safe range
            const H4u st = pack4u(acc[g][0]*inv, acc[g][1]*inv, acc[g][2]*inv, acc[g][3]*inv);
            *(h4*)(PACC + (rb + qr)*DD + head*DH + quad*4) = st.v;
            if (quad == 0) PL[(rb + qr)*HH + head] = l;
        }
    }
}

// ---------------- K3: merged-AO @ Wout + b via K=32 MFMA ----------------
// 1 wave per m-tile (257 blocks = 1 wave/SIMD): latency-bound, so hoist ALL
// loads (PACC, PL, Wout) into unrolled reg arrays for max MLP; occupancy
// is irrelevant here -> launch_bounds(256,1) frees the VGPR budget.
__global__ __launch_bounds__(256, 1) void out_mfma(
    const _Float16* __restrict__ PACC,
    const float* __restrict__ PL,
    const _Float16* __restrict__ WoutT,   // [128][128]
    const float* __restrict__ bout,
    float* __restrict__ out)
{
    const int wid  = blockIdx.x*4 + (threadIdx.x >> 6);   // m-tile
    if (wid >= MT) return;
    const int lane = threadIdx.x & 63;
    const int quad = lane >> 4, l16 = lane & 15;
    const int hq   = quad >> 1;

    const int arow = wid*16 + l16;
    const int arc  = (arow < ROWS) ? arow : (ROWS - 1);

    // ---- hoisted loads: 8 h8 PACC + 8 PL scalars + 32 h8 Wout, all independent
    h8 pf[NSP][4]; float lv[NSP][4];
    #pragma unroll
    for (int sp = 0; sp < NSP; ++sp) {
        const _Float16* pb  = PACC + ((size_t)sp*ROWS + arc)*DD;
        const float*    plb = PL   + ((size_t)sp*ROWS + arc)*HH;
        #pragma unroll
        for (int kk = 0; kk < 4; ++kk) {
            pf[sp][kk] = *(const h8*)(pb + kk*32 + quad*8);
            lv[sp][kk] = plb[kk*2 + hq];
        }
    }
    h8 wf[4][2][4];   // [nt-pair][u][kk]
    #pragma unroll
    for (int p = 0; p < 4; ++p)
        #pragma unroll
        for (int u = 0; u < 2; ++u)
            #pragma unroll
            for (int kk = 0; kk < 4; ++kk)
                wf[p][u][kk] = *(const h8*)(WoutT + (size_t)((p*2+u)*16 + l16)*DD + kk*32 + quad*8);

    // ---- merge splits into the A-fragment (head = kk*2 + hq per k-chunk)
    h8 af[4];
    #pragma unroll
    for (int kk = 0; kk < 4; ++kk) {
        const float l0 = lv[0][kk], l1 = lv[1][kk];
        const float inv = 1.0f / (l0 + l1);
        const float s0 = l0*inv, s1 = l1*inv;
        H8u u;
        #pragma unroll
        for (int j = 0; j < 4; ++j) {
            const float a = s0*(float)pf[0][kk][2*j]   + s1*(float)pf[1][kk][2*j];
            const float b = s0*(float)pf[0][kk][2*j+1] + s1*(float)pf[1][kk][2*j+1];
#if __has_builtin(__builtin_amdgcn_cvt_pkrtz)
            u.p[j] = __builtin_amdgcn_cvt_pkrtz(a, b);
#else
            u.v[2*j] = (_Float16)a; u.v[2*j+1] = (_Float16)b;
#endif
        }
        af[kk] = u.v;
    }

    const int r0 = wid*16 + quad*4;

    #pragma unroll
    for (int p = 0; p < 4; ++p) {
        const int nt = p*2;
        const float b0 = bout[nt*16 + l16];
        const float b1 = bout[nt*16 + 16 + l16];
        f4 a0 = {b0,b0,b0,b0}, a1 = {b1,b1,b1,b1};
        #pragma unroll
        for (int kk = 0; kk < 4; ++kk) {
            a0 = __builtin_amdgcn_mfma_f32_16x16x32_f16(af[kk], wf[p][0][kk], a0, 0, 0, 0);
            a1 = __builtin_amdgcn_mfma_f32_16x16x32_f16(af[kk], wf[p][1][kk], a1, 0, 0, 0);
        }
        #pragma unroll
        for (int r = 0; r < 4; ++r) {
            const int row = r0 + r;
            if (row < ROWS) {
                out[(size_t)row*DD + nt*16      + l16] = a0[r];
                out[(size_t)row*DD + nt*16 + 16 + l16] = a1[r];
            }
        }
    }
}

extern "C" void kernel_launch(void* const* d_in, const int* in_sizes, int n_in,
                              void* d_out, int out_size, void* d_ws, size_t ws_size,
                              hipStream_t stream) {
    const float* x    = (const float*)d_in[0];
    const float* Wqkv = (const float*)d_in[1];
    const float* bqkv = (const float*)d_in[2];
    const float* Wout = (const float*)d_in[3];
    const float* bout = (const float*)d_in[4];
    for (int i = 0; i < n_in; ++i) {
        switch (in_sizes[i]) {
            case 2097664: x    = (const float*)d_in[i]; break;
            case 49152:   Wqkv = (const float*)d_in[i]; break;
            case 384:     bqkv = (const float*)d_in[i]; break;
            case 16384:   Wout = (const float*)d_in[i]; break;
            case 128:     bout = (const float*)d_in[i]; break;
            default: break;
        }
    }
    float* out = (float*)d_out;

    const size_t perh = (size_t)BH * NNP * DH;            // 2,105,344 f16
    _Float16* Qh   = (_Float16*)d_ws;                     // 4.21 MB
    _Float16* Kh   = Qh + perh;                           // 4.21 MB
    _Float16* Vt   = Kh + perh;                           // 4.21 MB
    _Float16* Vh   = Vt + perh;                           // 4.21 MB (dead after vt)
    _Float16* PACC = Vh;                                  // [NSP][ROWS][DD] f16 8.4 MB
    _Float16* x16  = Vh + perh;                           // 4.2 MB, inside PACC tail
                                                          // (dead before attn writes PACC)
    float*    PL    = (float*)(PACC + (size_t)NSP*ROWS*DD); // 1.05 MB
    _Float16* WqkvT = (_Float16*)(PL + (size_t)NSP*ROWS*HH);// 96 KB
    _Float16* WoutT = WqkvT + 384*128;                    // 32 KB -> total ~23 MB

    const int NX8 = ROWS*DD/8;
    const int prep_total = NX8 + 384*128 + 128*128;

    hipLaunchKernelGGL(prep, dim3((prep_total + 255)/256), dim3(256), 0, stream,
                       x, Wqkv, Wout, x16, WqkvT, WoutT);
    hipLaunchKernelGGL(qkv_mfma, dim3(MT), dim3(256), 0, stream,
                       x16, WqkvT, bqkv, Qh, Kh, Vh);
    hipLaunchKernelGGL(vt_transpose, dim3(33, BH), dim3(256), 0, stream,
                       Vh, Vt);
    hipLaunchKernelGGL(attn_mfma, dim3(17, BH, NSP), dim3(256), 0, stream,
                       Qh, Kh, Vt, PACC, PL);
    hipLaunchKernelGGL(out_mfma, dim3((MT + 3)/4), dim3(256), 0, stream,
                       PACC, PL, WoutT, bout, out);
}

// Round 4
// 179.365 us; speedup vs baseline: 1.2443x; 1.0333x over previous
//
#include <hip/hip_runtime.h>
#include <hip/hip_bf16.h>
#include <stdint.h>

// Attention: b=4, n=4097, d=128, h=8, dh=16, scale = d**-0.5.
// Interface (R5): fp32 in, fp32 out, ws >= 33.6MB usable.
// R17: (1) attn reverted to the R13-proven NSP=4 structure (R16's NSP=2
// halved residency: occ 50->27%, 89.3->98.8us; this kernel is SIMD-issue
// bound, VALU 55us + MFMA 30us ~= 85us floor, and needs waves to overlap
// the pipes). (2) qkv converts x fp32->f16 inline (prep's 12.6MB x16 pass
// deleted). (3) qkv stores via LDS stage: 24 ds_write_b16 + ~3 fat 32B
// global stores/thread instead of 96 scattered 2B scalar stores/thread
// (dest ((bh*NNP+nrow)*16)*2B is always 32B-aligned; per-token units make
// batch-spanning m-tiles correct naturally). out_mfma = R16 full-hoist at
// NSP=4. attn_mfma/vt_transpose bodies otherwise frozen.

#define BB 4
#define NN 4097
#define NNP 4112
#define DD 128
#define HH 8
#define DH 16
#define BH (BB*HH)    // 32
#define ROWS (BB*NN)  // 16388
#define MT  1025      // ceil(ROWS/16) m-tiles
#define NSP 4         // attention key-splits (R13-proven)

typedef _Float16 h4 __attribute__((ext_vector_type(4)));
typedef _Float16 h8 __attribute__((ext_vector_type(8)));
typedef __fp16   fp16v2 __attribute__((ext_vector_type(2)));
typedef float    f4 __attribute__((ext_vector_type(4)));

#define QSCALE (0.08838834764831845f * 1.4426950408889634f)  // 128^-.5 * log2e

#if __has_builtin(__builtin_amdgcn_exp2f)
#define EXP2F(x) __builtin_amdgcn_exp2f(x)
#else
#define EXP2F(x) exp2f(x)
#endif

union H4u { h4 v; fp16v2 p[2]; };
union H8u { h8 v; fp16v2 p[4]; };

static __device__ __forceinline__ H4u pack4u(float a, float b, float c, float d) {
    H4u u;
#if __has_builtin(__builtin_amdgcn_cvt_pkrtz)
    u.p[0] = __builtin_amdgcn_cvt_pkrtz(a, b);
    u.p[1] = __builtin_amdgcn_cvt_pkrtz(c, d);
#else
    u.v[0] = (_Float16)a; u.v[1] = (_Float16)b; u.v[2] = (_Float16)c; u.v[3] = (_Float16)d;
#endif
    return u;
}

static __device__ __forceinline__ h8 pack8u(const float4& t0, const float4& t1) {
    H8u u;
#if __has_builtin(__builtin_amdgcn_cvt_pkrtz)
    u.p[0] = __builtin_amdgcn_cvt_pkrtz(t0.x, t0.y);
    u.p[1] = __builtin_amdgcn_cvt_pkrtz(t0.z, t0.w);
    u.p[2] = __builtin_amdgcn_cvt_pkrtz(t1.x, t1.y);
    u.p[3] = __builtin_amdgcn_cvt_pkrtz(t1.z, t1.w);
#else
    u.v[0]=(_Float16)t0.x; u.v[1]=(_Float16)t0.y; u.v[2]=(_Float16)t0.z; u.v[3]=(_Float16)t0.w;
    u.v[4]=(_Float16)t1.x; u.v[5]=(_Float16)t1.y; u.v[6]=(_Float16)t1.z; u.v[7]=(_Float16)t1.w;
#endif
    return u.v;
}

// ---------------- K0: prep — W_qkv^T (Q-scaled) + W_out^T in f16 -------
__global__ __launch_bounds__(256) void prep(
    const float* __restrict__ Wqkv,
    const float* __restrict__ Wout,
    _Float16* __restrict__ WqkvT,   // [384][128], rows 0..127 pre-scaled by QSCALE
    _Float16* __restrict__ WoutT)   // [128][128]
{
    const int id = blockIdx.x*256 + threadIdx.x;
    if (id < 384*128) {
        const int n = id >> 7, k = id & 127;
        const float s = (n < 128) ? QSCALE : 1.0f;
        WqkvT[id] = (_Float16)(Wqkv[k*384 + n] * s);
    } else if (id < 384*128 + 128*128) {
        const int e = id - 384*128;
        const int n = e >> 7, k = e & 127;
        WoutT[e] = (_Float16)(Wout[k*128 + n]);
    }
}

// ---------------- K1: qkv = x @ WqkvT^T + b, via K=32 MFMA ----------------
// D[m=quad*4+reg][n=l16]; A[m=l16][k=quad*8+j]; B[k=quad*8+j][n=l16].
// One block per m-tile; 4 waves split the 24 nt. Outputs staged in LDS then
// written as per-token 32B-aligned h8 pairs (R17).
__global__ __launch_bounds__(256) void qkv_mfma(
    const float* __restrict__ x,
    const _Float16* __restrict__ WqkvT,
    const float* __restrict__ bqkv,
    _Float16* __restrict__ Qh,    // [BH][NNP][16]
    _Float16* __restrict__ Kh,    // [BH][NNP][16]
    _Float16* __restrict__ Vh)    // [BH][NNP][16] row-major
{
    __shared__ _Float16 tile[16][392];            // [local token][ntc*16+dim], pad->bank spread
    const int wid  = blockIdx.x;                  // m-tile 0..1024
    const int wave = threadIdx.x >> 6;            // 0..3 -> nt chunk
    const int lane = threadIdx.x & 63;
    const int quad = lane >> 4, l16 = lane & 15;

    const int arow = wid*16 + l16;
    const int arc  = (arow < ROWS) ? arow : (ROWS - 1);
    const float* xr = x + (size_t)arc*DD;
    h8 af[4];
    #pragma unroll
    for (int kk = 0; kk < 4; ++kk) {
        const float4 t0 = *(const float4*)(xr + kk*32 + quad*8);
        const float4 t1 = *(const float4*)(xr + kk*32 + quad*8 + 4);
        af[kk] = pack8u(t0, t1);
    }

    const int nt0 = wave*6;

    for (int nt = nt0; nt < nt0 + 6; nt += 2) {
        const float b0 = bqkv[nt*16 + l16]      * ((nt   < 8) ? QSCALE : 1.0f);
        const float b1 = bqkv[nt*16 + 16 + l16] * ((nt+1 < 8) ? QSCALE : 1.0f);
        f4 a0 = {b0,b0,b0,b0}, a1 = {b1,b1,b1,b1};
        #pragma unroll
        for (int kk = 0; kk < 4; ++kk) {
            const h8 bf0 = *(const h8*)(WqkvT + (size_t)(nt*16      + l16)*DD + kk*32 + quad*8);
            const h8 bf1 = *(const h8*)(WqkvT + (size_t)(nt*16 + 16 + l16)*DD + kk*32 + quad*8);
            a0 = __builtin_amdgcn_mfma_f32_16x16x32_f16(af[kk], bf0, a0, 0, 0, 0);
            a1 = __builtin_amdgcn_mfma_f32_16x16x32_f16(af[kk], bf1, a1, 0, 0, 0);
        }
        #pragma unroll
        for (int u = 0; u < 2; ++u) {
            const int ntc = nt + u;
            const f4 av = u ? a1 : a0;
            #pragma unroll
            for (int r = 0; r < 4; ++r)
                tile[quad*4 + r][ntc*16 + l16] = (_Float16)av[r];
        }
    }
    __syncthreads();

    // write phase: unit = (ntc, local token); one 16-dim head-row = 2x h8 (32B, aligned)
    for (int u = threadIdx.x; u < 384; u += 256) {
        const int ntc = u >> 4, lt = u & 15;
        const int row = wid*16 + lt;
        if (row < ROWS) {
            const int which = ntc >> 3, head = ntc & 7;
            _Float16* base = (which == 0) ? Qh : ((which == 1) ? Kh : Vh);
            const int bidx = row / NN;
            const int nrow = row - bidx*NN;
            _Float16* dst = base + ((size_t)(bidx*HH + head)*NNP + nrow)*DH;
            *(h8*)dst       = *(const h8*)&tile[lt][ntc*16];
            *(h8*)(dst + 8) = *(const h8*)&tile[lt][ntc*16 + 8];
        }
    }
}

// ---------------- K1b: Vh [bh][n][16] -> Vt [bh][16][NNP] (R10-proven) ---------
__global__ __launch_bounds__(256) void vt_transpose(
    const _Float16* __restrict__ Vh,
    _Float16* __restrict__ Vt)
{
    __shared__ _Float16 tile[128][DH + 2];
    const int tl  = blockIdx.x;              // 0..32
    const int bh  = blockIdx.y;              // 0..31
    const int tid = threadIdx.x;             // 0..255
    const int n0  = tl * 128;
    const int rem = (n0 + 128 <= NNP) ? 128 : (NNP - n0);

    {
        const int r  = tid >> 1;
        const int i8 = (tid & 1) * 8;
        const int rc = (r < rem) ? r : (rem - 1);
        const h8 v = *(const h8*)(Vh + ((size_t)bh*NNP + n0 + rc)*DH + i8);
        #pragma unroll
        for (int j = 0; j < 8; ++j) tile[r][i8 + j] = v[j];
    }
    __syncthreads();
    {
        const int i    = tid >> 4;      // 0..15
        const int nseg = tid & 15;      // 0..15
        if (nseg * 8 < rem) {
            h8 v;
            #pragma unroll
            for (int j = 0; j < 8; ++j) v[j] = tile[nseg*8 + j][i];
            *(h8*)(Vt + ((size_t)bh*DH + i)*NNP + n0 + nseg*8) = v;
        }
    }
}

// ---------------- K2: MFMA flash attention (R13-frozen, NSP=4) ----------------
__global__ __launch_bounds__(256, 8) void attn_mfma(
    const _Float16* __restrict__ Qh,
    const _Float16* __restrict__ Kh,
    const _Float16* __restrict__ Vt,
    _Float16* __restrict__ PACC,   // [NSP][ROWS][DD] per-split normalized out (f16)
    float* __restrict__ PL)        // [NSP][ROWS][HH] per-split row sums
{
    const int qt   = blockIdx.x;       // 0..16
    const int bh   = blockIdx.y;       // 0..31
    const int sp   = blockIdx.z;       // 0..3
    const int tid  = threadIdx.x;
    const int wave = tid >> 6;
    const int lane = tid & 63;
    const int quad = lane >> 4;
    const int l16  = lane & 15;
    const int bidx = bh >> 3, head = bh & 7;

    const int qbase = qt*256 + wave*64;

    const _Float16* Qb = Qh + (size_t)bh*NNP*DH;
    h4 qf[4];
    #pragma unroll
    for (int g = 0; g < 4; ++g) {
        const int qr = qbase + g*16 + l16;
        const int qc = (qr < NN) ? qr : (NN-1);
        qf[g] = *(const h4*)(Qb + (size_t)qc*DH + quad*4);
    }

    f4 acc[4] = {{0,0,0,0},{0,0,0,0},{0,0,0,0},{0,0,0,0}};
    float ls[4] = {0.f,0.f,0.f,0.f};

    const int t0 = sp*64;
    const int t1 = t0 + 64;

    const _Float16* kp = Kh + ((size_t)bh*NNP + (size_t)t0*16 + l16)*DH + quad*4;
    const _Float16* vp = Vt + ((size_t)bh*DH + l16)*NNP + t0*16 + quad*4;

    h4 ak = *(const h4*)kp;
    h4 av = *(const h4*)vp;
    const f4 zero = {0.f,0.f,0.f,0.f};
#if __has_builtin(__builtin_amdgcn_fdot2)
    const fp16v2 one2 = {(__fp16)1.0f, (__fp16)1.0f};
#endif

    for (int tt = t0; tt < t1; ++tt) {
        kp += 16*DH; vp += 16;
        const h4 nak = *(const h4*)kp;   // prefetch (tile <= 256 in-bounds)
        const h4 nav = *(const h4*)vp;
        #pragma unroll
        for (int g = 0; g < 4; ++g) {
            f4 d = __builtin_amdgcn_mfma_f32_16x16x16f16(ak, qf[g], zero, 0, 0, 0);
            const float p0 = EXP2F(d[0]), p1 = EXP2F(d[1]), p2 = EXP2F(d[2]), p3 = EXP2F(d[3]);
            const H4u pb = pack4u(p0, p1, p2, p3);
#if __has_builtin(__builtin_amdgcn_fdot2)
            ls[g] = __builtin_amdgcn_fdot2(pb.p[0], one2,
                     __builtin_amdgcn_fdot2(pb.p[1], one2, ls[g], false), false);
#else
            ls[g] += (p0 + p1) + (p2 + p3);
#endif
            acc[g] = __builtin_amdgcn_mfma_f32_16x16x16f16(av, pb.v, acc[g], 0, 0, 0);
        }
        ak = nak; av = nav;
    }

    if (sp == 3) {   // tile 256: keys 4096..4111; only key 4096 (quad==0, reg 0) valid
        #pragma unroll
        for (int g = 0; g < 4; ++g) {
            f4 d = __builtin_amdgcn_mfma_f32_16x16x16f16(ak, qf[g], zero, 0, 0, 0);
            const float p0 = (quad == 0) ? EXP2F(d[0]) : 0.f;
            ls[g] += p0;
            const H4u pb = pack4u(p0, 0.f, 0.f, 0.f);
            acc[g] = __builtin_amdgcn_mfma_f32_16x16x16f16(av, pb.v, acc[g], 0, 0, 0);
        }
    }

    const size_t rb = (size_t)sp*ROWS + (size_t)bidx*NN;
    #pragma unroll
    for (int g = 0; g < 4; ++g) {
        float l = ls[g];
        l += __shfl_xor(l, 16);
        l += __shfl_xor(l, 32);
        const int qr = qbase + g*16 + l16;
        if (qr < NN) {
            const float inv = 1.0f / l;   // per-split normalize: f16-safe range
            const H4u st = pack4u(acc[g][0]*inv, acc[g][1]*inv, acc[g][2]*inv, acc[g][3]*inv);
            *(h4*)(PACC + (rb + qr)*DD + head*DH + quad*4) = st.v;
            if (quad == 0) PL[(rb + qr)*HH + head] = l;
        }
    }
}

// ---------------- K3: merged-AO @ Wout + b via K=32 MFMA ----------------
// 1 wave per m-tile (257 blocks = 1 wave/SIMD): latency-bound, so hoist ALL
// loads (PACC, PL, Wout) into unrolled reg arrays for max MLP; occupancy
// is irrelevant here -> launch_bounds(256,1) frees the VGPR budget.
__global__ __launch_bounds__(256, 1) void out_mfma(
    const _Float16* __restrict__ PACC,
    const float* __restrict__ PL,
    const _Float16* __restrict__ WoutT,   // [128][128]
    const float* __restrict__ bout,
    float* __restrict__ out)
{
    const int wid  = blockIdx.x*4 + (threadIdx.x >> 6);   // m-tile
    if (wid >= MT) return;
    const int lane = threadIdx.x & 63;
    const int quad = lane >> 4, l16 = lane & 15;
    const int hq   = quad >> 1;

    const int arow = wid*16 + l16;
    const int arc  = (arow < ROWS) ? arow : (ROWS - 1);

    // ---- hoisted loads: 16 h8 PACC + 16 PL scalars + 32 h8 Wout, all independent
    h8 pf[NSP][4]; float lv[NSP][4];
    #pragma unroll
    for (int sp = 0; sp < NSP; ++sp) {
        const _Float16* pb  = PACC + ((size_t)sp*ROWS + arc)*DD;
        const float*    plb = PL   + ((size_t)sp*ROWS + arc)*HH;
        #pragma unroll
        for (int kk = 0; kk < 4; ++kk) {
            pf[sp][kk] = *(const h8*)(pb + kk*32 + quad*8);
            lv[sp][kk] = plb[kk*2 + hq];
        }
    }
    h8 wf[4][2][4];   // [nt-pair][u][kk]
    #pragma unroll
    for (int p = 0; p < 4; ++p)
        #pragma unroll
        for (int u = 0; u < 2; ++u)
            #pragma unroll
            for (int kk = 0; kk < 4; ++kk)
                wf[p][u][kk] = *(const h8*)(WoutT + (size_t)((p*2+u)*16 + l16)*DD + kk*32 + quad*8);

    // ---- merge splits into the A-fragment (head = kk*2 + hq per k-chunk)
    h8 af[4];
    #pragma unroll
    for (int kk = 0; kk < 4; ++kk) {
        float lsum = 0.f;
        #pragma unroll
        for (int sp = 0; sp < NSP; ++sp) lsum += lv[sp][kk];
        const float inv = 1.0f / lsum;
        H8u u;
        #pragma unroll
        for (int j = 0; j < 4; ++j) {
            float a = 0.f, b = 0.f;
            #pragma unroll
            for (int sp = 0; sp < NSP; ++sp) {
                const float s = lv[sp][kk]*inv;
                a += s*(float)pf[sp][kk][2*j];
                b += s*(float)pf[sp][kk][2*j+1];
            }
#if __has_builtin(__builtin_amdgcn_cvt_pkrtz)
            u.p[j] = __builtin_amdgcn_cvt_pkrtz(a, b);
#else
            u.v[2*j] = (_Float16)a; u.v[2*j+1] = (_Float16)b;
#endif
        }
        af[kk] = u.v;
    }

    const int r0 = wid*16 + quad*4;

    #pragma unroll
    for (int p = 0; p < 4; ++p) {
        const int nt = p*2;
        const float b0 = bout[nt*16 + l16];
        const float b1 = bout[nt*16 + 16 + l16];
        f4 a0 = {b0,b0,b0,b0}, a1 = {b1,b1,b1,b1};
        #pragma unroll
        for (int kk = 0; kk < 4; ++kk) {
            a0 = __builtin_amdgcn_mfma_f32_16x16x32_f16(af[kk], wf[p][0][kk], a0, 0, 0, 0);
            a1 = __builtin_amdgcn_mfma_f32_16x16x32_f16(af[kk], wf[p][1][kk], a1, 0, 0, 0);
        }
        #pragma unroll
        for (int r = 0; r < 4; ++r) {
            const int row = r0 + r;
            if (row < ROWS) {
                out[(size_t)row*DD + nt*16      + l16] = a0[r];
                out[(size_t)row*DD + nt*16 + 16 + l16] = a1[r];
            }
        }
    }
}

extern "C" void kernel_launch(void* const* d_in, const int* in_sizes, int n_in,
                              void* d_out, int out_size, void* d_ws, size_t ws_size,
                              hipStream_t stream) {
    const float* x    = (const float*)d_in[0];
    const float* Wqkv = (const float*)d_in[1];
    const float* bqkv = (const float*)d_in[2];
    const float* Wout = (const float*)d_in[3];
    const float* bout = (const float*)d_in[4];
    for (int i = 0; i < n_in; ++i) {
        switch (in_sizes[i]) {
            case 2097664: x    = (const float*)d_in[i]; break;
            case 49152:   Wqkv = (const float*)d_in[i]; break;
            case 384:     bqkv = (const float*)d_in[i]; break;
            case 16384:   Wout = (const float*)d_in[i]; break;
            case 128:     bout = (const float*)d_in[i]; break;
            default: break;
        }
    }
    float* out = (float*)d_out;

    const size_t perh = (size_t)BH * NNP * DH;            // 2,105,344 f16
    _Float16* Qh   = (_Float16*)d_ws;                     // 4.21 MB
    _Float16* Kh   = Qh + perh;                           // 4.21 MB
    _Float16* Vt   = Kh + perh;                           // 4.21 MB
    _Float16* Vh   = Vt + perh;                           // 4.21 MB (dead after vt)
    _Float16* PACC = Vh;                                  // [NSP][ROWS][DD] f16 16.78 MB
    float*    PL    = (float*)(PACC + (size_t)NSP*ROWS*DD); // 2.1 MB
    _Float16* WqkvT = (_Float16*)(PL + (size_t)NSP*ROWS*HH);// 96 KB
    _Float16* WoutT = WqkvT + 384*128;                    // 32 KB -> total ~31.6 MB

    const int prep_total = 384*128 + 128*128;

    hipLaunchKernelGGL(prep, dim3((prep_total + 255)/256), dim3(256), 0, stream,
                       Wqkv, Wout, WqkvT, WoutT);
    hipLaunchKernelGGL(qkv_mfma, dim3(MT), dim3(256), 0, stream,
                       x, WqkvT, bqkv, Qh, Kh, Vh);
    hipLaunchKernelGGL(vt_transpose, dim3(33, BH), dim3(256), 0, stream,
                       Vh, Vt);
    hipLaunchKernelGGL(attn_mfma, dim3(17, BH, NSP), dim3(256), 0, stream,
                       Qh, Kh, Vt, PACC, PL);
    hipLaunchKernelGGL(out_mfma, dim3((MT + 3)/4), dim3(256), 0, stream,
                       PACC, PL, WoutT, bout, out);
}

// Round 5
// 176.179 us; speedup vs baseline: 1.2668x; 1.0181x over previous
//
#include <hip/hip_runtime.h>
#include <hip/hip_bf16.h>
#include <stdint.h>

// Attention: b=4, n=4097, d=128, h=8, dh=16, scale = d**-0.5.
// Interface (R5): fp32 in, fp32 out, ws >= 33.6MB usable.
// R18: attn is issue-port-saturated (R17: VALU 66% + MFMA 35%; exp2 floor
// ~27us) -> frozen at the R13/R17 body. All effort on the ~92us non-attn:
//  (1) vt_transpose kernel DELETED: qkv's compute phase already holds V for
//      4 consecutive tokens at fixed dim l16 per thread = one 8B h4 store
//      directly into Vt [bh][16][NNP] (scalar path for the 4 batch-boundary
//      m-tiles). Saves a launch + 12.6MB of pure copy traffic + Vh buffer.
//  (2) out_mfma: was 257 blocks = 1 wave/SIMD latency-bound (R16 hoist
//      helped but structure caps it). Now 1025 blocks: per-m-tile split
//      merge computed ONCE into LDS (no R14-style redundancy), then 4
//      waves each do 2 n-tiles of the Wout GEMM. 4x wave parallelism at
//      identical HBM traffic.

#define BB 4
#define NN 4097
#define NNP 4112
#define DD 128
#define HH 8
#define DH 16
#define BH (BB*HH)    // 32
#define ROWS (BB*NN)  // 16388
#define MT  1025      // ceil(ROWS/16) m-tiles
#define NSP 4         // attention key-splits (R13-proven)

typedef _Float16 h4 __attribute__((ext_vector_type(4)));
typedef _Float16 h8 __attribute__((ext_vector_type(8)));
typedef __fp16   fp16v2 __attribute__((ext_vector_type(2)));
typedef float    f4 __attribute__((ext_vector_type(4)));

#define QSCALE (0.08838834764831845f * 1.4426950408889634f)  // 128^-.5 * log2e

#if __has_builtin(__builtin_amdgcn_exp2f)
#define EXP2F(x) __builtin_amdgcn_exp2f(x)
#else
#define EXP2F(x) exp2f(x)
#endif

union H4u { h4 v; fp16v2 p[2]; };
union H8u { h8 v; fp16v2 p[4]; };

static __device__ __forceinline__ H4u pack4u(float a, float b, float c, float d) {
    H4u u;
#if __has_builtin(__builtin_amdgcn_cvt_pkrtz)
    u.p[0] = __builtin_amdgcn_cvt_pkrtz(a, b);
    u.p[1] = __builtin_amdgcn_cvt_pkrtz(c, d);
#else
    u.v[0] = (_Float16)a; u.v[1] = (_Float16)b; u.v[2] = (_Float16)c; u.v[3] = (_Float16)d;
#endif
    return u;
}

static __device__ __forceinline__ h8 pack8u(const float4& t0, const float4& t1) {
    H8u u;
#if __has_builtin(__builtin_amdgcn_cvt_pkrtz)
    u.p[0] = __builtin_amdgcn_cvt_pkrtz(t0.x, t0.y);
    u.p[1] = __builtin_amdgcn_cvt_pkrtz(t0.z, t0.w);
    u.p[2] = __builtin_amdgcn_cvt_pkrtz(t1.x, t1.y);
    u.p[3] = __builtin_amdgcn_cvt_pkrtz(t1.z, t1.w);
#else
    u.v[0]=(_Float16)t0.x; u.v[1]=(_Float16)t0.y; u.v[2]=(_Float16)t0.z; u.v[3]=(_Float16)t0.w;
    u.v[4]=(_Float16)t1.x; u.v[5]=(_Float16)t1.y; u.v[6]=(_Float16)t1.z; u.v[7]=(_Float16)t1.w;
#endif
    return u.v;
}

// ---------------- K0: prep — W_qkv^T (Q-scaled) + W_out^T in f16 -------
__global__ __launch_bounds__(256) void prep(
    const float* __restrict__ Wqkv,
    const float* __restrict__ Wout,
    _Float16* __restrict__ WqkvT,   // [384][128], rows 0..127 pre-scaled by QSCALE
    _Float16* __restrict__ WoutT)   // [128][128]
{
    const int id = blockIdx.x*256 + threadIdx.x;
    if (id < 384*128) {
        const int n = id >> 7, k = id & 127;
        const float s = (n < 128) ? QSCALE : 1.0f;
        WqkvT[id] = (_Float16)(Wqkv[k*384 + n] * s);
    } else if (id < 384*128 + 128*128) {
        const int e = id - 384*128;
        const int n = e >> 7, k = e & 127;
        WoutT[e] = (_Float16)(Wout[k*128 + n]);
    }
}

// ---------------- K1: qkv = x @ WqkvT^T + b, via K=32 MFMA ----------------
// D[m=quad*4+reg][n=l16]; A[m=l16][k=quad*8+j]; B[k=quad*8+j][n=l16].
// One block per m-tile; 4 waves split the 24 nt. Q/K staged in LDS then
// written as per-token 32B h8 pairs; V stored DIRECTLY into the transposed
// Vt layout (thread holds 4 consecutive tokens at fixed dim = h4 store).
__global__ __launch_bounds__(256) void qkv_mfma(
    const float* __restrict__ x,
    const _Float16* __restrict__ WqkvT,
    const float* __restrict__ bqkv,
    _Float16* __restrict__ Qh,    // [BH][NNP][16]
    _Float16* __restrict__ Kh,    // [BH][NNP][16]
    _Float16* __restrict__ Vt)    // [BH][16][NNP] (transposed, attn-ready)
{
    __shared__ _Float16 tile[16][264];            // [local token][ntc*16+dim] Q/K only
    const int wid  = blockIdx.x;                  // m-tile 0..1024
    const int wave = threadIdx.x >> 6;            // 0..3 -> nt chunk
    const int lane = threadIdx.x & 63;
    const int quad = lane >> 4, l16 = lane & 15;

    const int rowlo = wid*16;
    const int blo   = rowlo / NN;
    const bool vfast = (rowlo + 15 < ROWS) && (rowlo + 15 - blo*NN < NN);
    const int nrow0 = rowlo - blo*NN;

    const int arow = rowlo + l16;
    const int arc  = (arow < ROWS) ? arow : (ROWS - 1);
    const float* xr = x + (size_t)arc*DD;
    h8 af[4];
    #pragma unroll
    for (int kk = 0; kk < 4; ++kk) {
        const float4 t0 = *(const float4*)(xr + kk*32 + quad*8);
        const float4 t1 = *(const float4*)(xr + kk*32 + quad*8 + 4);
        af[kk] = pack8u(t0, t1);
    }

    const int nt0 = wave*6;

    for (int nt = nt0; nt < nt0 + 6; nt += 2) {
        const float b0 = bqkv[nt*16 + l16]      * ((nt   < 8) ? QSCALE : 1.0f);
        const float b1 = bqkv[nt*16 + 16 + l16] * ((nt+1 < 8) ? QSCALE : 1.0f);
        f4 a0 = {b0,b0,b0,b0}, a1 = {b1,b1,b1,b1};
        #pragma unroll
        for (int kk = 0; kk < 4; ++kk) {
            const h8 bf0 = *(const h8*)(WqkvT + (size_t)(nt*16      + l16)*DD + kk*32 + quad*8);
            const h8 bf1 = *(const h8*)(WqkvT + (size_t)(nt*16 + 16 + l16)*DD + kk*32 + quad*8);
            a0 = __builtin_amdgcn_mfma_f32_16x16x32_f16(af[kk], bf0, a0, 0, 0, 0);
            a1 = __builtin_amdgcn_mfma_f32_16x16x32_f16(af[kk], bf1, a1, 0, 0, 0);
        }
        #pragma unroll
        for (int u = 0; u < 2; ++u) {
            const int ntc = nt + u;
            const f4 av = u ? a1 : a0;
            if (ntc < 16) {        // Q/K -> LDS stage
                #pragma unroll
                for (int r = 0; r < 4; ++r)
                    tile[quad*4 + r][ntc*16 + l16] = (_Float16)av[r];
            } else {               // V -> direct transposed store
                const int head = ntc & 7;
                if (vfast) {
                    h4 pk;         // RTN converts (match prior V rounding class)
                    pk[0] = (_Float16)av[0]; pk[1] = (_Float16)av[1];
                    pk[2] = (_Float16)av[2]; pk[3] = (_Float16)av[3];
                    *(h4*)(Vt + ((size_t)(blo*HH + head)*DH + l16)*NNP + nrow0 + quad*4) = pk;
                } else {
                    #pragma unroll
                    for (int r = 0; r < 4; ++r) {
                        const int row = rowlo + quad*4 + r;
                        if (row < ROWS) {
                            const int bidx = row / NN;
                            const int nrow = row - bidx*NN;
                            Vt[((size_t)(bidx*HH + head)*DH + l16)*NNP + nrow] = (_Float16)av[r];
                        }
                    }
                }
            }
        }
    }
    __syncthreads();

    // write phase (Q/K): unit = (ntc, local token); 16-dim head-row = 2x h8 (32B)
    {
        const int u   = threadIdx.x;   // 0..255 == 16 ntc x 16 tokens
        const int ntc = u >> 4, lt = u & 15;
        const int row = rowlo + lt;
        if (row < ROWS) {
            _Float16* base = (ntc < 8) ? Qh : Kh;
            const int head = ntc & 7;
            const int bidx = row / NN;
            const int nrow = row - bidx*NN;
            _Float16* dst = base + ((size_t)(bidx*HH + head)*NNP + nrow)*DH;
            *(h8*)dst       = *(const h8*)&tile[lt][ntc*16];
            *(h8*)(dst + 8) = *(const h8*)&tile[lt][ntc*16 + 8];
        }
    }
}

// ---------------- K2: MFMA flash attention (R13-frozen, NSP=4) ----------------
__global__ __launch_bounds__(256, 8) void attn_mfma(
    const _Float16* __restrict__ Qh,
    const _Float16* __restrict__ Kh,
    const _Float16* __restrict__ Vt,
    _Float16* __restrict__ PACC,   // [NSP][ROWS][DD] per-split normalized out (f16)
    float* __restrict__ PL)        // [NSP][ROWS][HH] per-split row sums
{
    const int qt   = blockIdx.x;       // 0..16
    const int bh   = blockIdx.y;       // 0..31
    const int sp   = blockIdx.z;       // 0..3
    const int tid  = threadIdx.x;
    const int wave = tid >> 6;
    const int lane = tid & 63;
    const int quad = lane >> 4;
    const int l16  = lane & 15;
    const int bidx = bh >> 3, head = bh & 7;

    const int qbase = qt*256 + wave*64;

    const _Float16* Qb = Qh + (size_t)bh*NNP*DH;
    h4 qf[4];
    #pragma unroll
    for (int g = 0; g < 4; ++g) {
        const int qr = qbase + g*16 + l16;
        const int qc = (qr < NN) ? qr : (NN-1);
        qf[g] = *(const h4*)(Qb + (size_t)qc*DH + quad*4);
    }

    f4 acc[4] = {{0,0,0,0},{0,0,0,0},{0,0,0,0},{0,0,0,0}};
    float ls[4] = {0.f,0.f,0.f,0.f};

    const int t0 = sp*64;
    const int t1 = t0 + 64;

    const _Float16* kp = Kh + ((size_t)bh*NNP + (size_t)t0*16 + l16)*DH + quad*4;
    const _Float16* vp = Vt + ((size_t)bh*DH + l16)*NNP + t0*16 + quad*4;

    h4 ak = *(const h4*)kp;
    h4 av = *(const h4*)vp;
    const f4 zero = {0.f,0.f,0.f,0.f};
#if __has_builtin(__builtin_amdgcn_fdot2)
    const fp16v2 one2 = {(__fp16)1.0f, (__fp16)1.0f};
#endif

    for (int tt = t0; tt < t1; ++tt) {
        kp += 16*DH; vp += 16;
        const h4 nak = *(const h4*)kp;   // prefetch (tile <= 256 in-bounds)
        const h4 nav = *(const h4*)vp;
        #pragma unroll
        for (int g = 0; g < 4; ++g) {
            f4 d = __builtin_amdgcn_mfma_f32_16x16x16f16(ak, qf[g], zero, 0, 0, 0);
            const float p0 = EXP2F(d[0]), p1 = EXP2F(d[1]), p2 = EXP2F(d[2]), p3 = EXP2F(d[3]);
            const H4u pb = pack4u(p0, p1, p2, p3);
#if __has_builtin(__builtin_amdgcn_fdot2)
            ls[g] = __builtin_amdgcn_fdot2(pb.p[0], one2,
                     __builtin_amdgcn_fdot2(pb.p[1], one2, ls[g], false), false);
#else
            ls[g] += (p0 + p1) + (p2 + p3);
#endif
            acc[g] = __builtin_amdgcn_mfma_f32_16x16x16f16(av, pb.v, acc[g], 0, 0, 0);
        }
        ak = nak; av = nav;
    }

    if (sp == 3) {   // tile 256: keys 4096..4111; only key 4096 (quad==0, reg 0) valid
        #pragma unroll
        for (int g = 0; g < 4; ++g) {
            f4 d = __builtin_amdgcn_mfma_f32_16x16x16f16(ak, qf[g], zero, 0, 0, 0);
            const float p0 = (quad == 0) ? EXP2F(d[0]) : 0.f;
            ls[g] += p0;
            const H4u pb = pack4u(p0, 0.f, 0.f, 0.f);
            acc[g] = __builtin_amdgcn_mfma_f32_16x16x16f16(av, pb.v, acc[g], 0, 0, 0);
        }
    }

    const size_t rb = (size_t)sp*ROWS + (size_t)bidx*NN;
    #pragma unroll
    for (int g = 0; g < 4; ++g) {
        float l = ls[g];
        l += __shfl_xor(l, 16);
        l += __shfl_xor(l, 32);
        const int qr = qbase + g*16 + l16;
        if (qr < NN) {
            const float inv = 1.0f / l;   // per-split normalize: f16-safe range
            const H4u st = pack4u(acc[g][0]*inv, acc[g][1]*inv, acc[g][2]*inv, acc[g][3]*inv);
            *(h4*)(PACC + (rb + qr)*DD + head*DH + quad*4) = st.v;
            if (quad == 0) PL[(rb + qr)*HH + head] = l;
        }
    }
}

// ---------------- K3: merged-AO @ Wout + b via K=32 MFMA ----------------
// R18: 1025 blocks. Phase 1: 256 threads cooperatively merge the NSP splits
// for this m-tile ONCE into LDS (coalesced 256B/row PACC reads). Phase 2:
// 4 waves each run 2 n-tiles of the Wout GEMM from the shared A-fragment.
__global__ __launch_bounds__(256) void out_mfma(
    const _Float16* __restrict__ PACC,
    const float* __restrict__ PL,
    const _Float16* __restrict__ WoutT,   // [128][128]
    const float* __restrict__ bout,
    float* __restrict__ out)
{
    __shared__ _Float16 afl[16][136];     // [token][dim], +8 pad
    const int wid  = blockIdx.x;          // m-tile 0..1024
    const int tid  = threadIdx.x;
    const int wave = tid >> 6;
    const int lane = tid & 63;
    const int quad = lane >> 4, l16 = lane & 15;
    const int nt   = wave*2;

    // hoist Wout + bias early (independent of merge phase)
    h8 wf[2][4];
    #pragma unroll
    for (int u = 0; u < 2; ++u)
        #pragma unroll
        for (int kk = 0; kk < 4; ++kk)
            wf[u][kk] = *(const h8*)(WoutT + (size_t)((nt+u)*16 + l16)*DD + kk*32 + quad*8);
    const float b0 = bout[nt*16 + l16];
    const float b1 = bout[nt*16 + 16 + l16];

    // ---- phase 1: merge splits for 16 tokens x 128 dims into LDS
    {
        const int t   = tid >> 4;         // local token 0..15
        const int seg = tid & 15;         // dim octet 0..15 (dims seg*8..+8)
        const int head = seg >> 1;
        const int arow = wid*16 + t;
        const int arc  = (arow < ROWS) ? arow : (ROWS - 1);
        float l[NSP], lsum = 0.f;
        #pragma unroll
        for (int sp = 0; sp < NSP; ++sp) {
            l[sp] = PL[((size_t)sp*ROWS + arc)*HH + head];
            lsum += l[sp];
        }
        const float inv = 1.0f / lsum;
        float m[8] = {0,0,0,0,0,0,0,0};
        #pragma unroll
        for (int sp = 0; sp < NSP; ++sp) {
            const float s = l[sp]*inv;
            const h8 p = *(const h8*)(PACC + ((size_t)sp*ROWS + arc)*DD + seg*8);
            #pragma unroll
            for (int j = 0; j < 8; ++j) m[j] += s*(float)p[j];
        }
        H8u u;
#if __has_builtin(__builtin_amdgcn_cvt_pkrtz)
        u.p[0] = __builtin_amdgcn_cvt_pkrtz(m[0], m[1]);
        u.p[1] = __builtin_amdgcn_cvt_pkrtz(m[2], m[3]);
        u.p[2] = __builtin_amdgcn_cvt_pkrtz(m[4], m[5]);
        u.p[3] = __builtin_amdgcn_cvt_pkrtz(m[6], m[7]);
#else
        #pragma unroll
        for (int j = 0; j < 8; ++j) u.v[j] = (_Float16)m[j];
#endif
        *(h8*)&afl[t][seg*8] = u.v;
    }
    __syncthreads();

    // ---- phase 2: GEMM vs WoutT; wave handles n-tiles nt, nt+1
    h8 af[4];
    #pragma unroll
    for (int kk = 0; kk < 4; ++kk)
        af[kk] = *(const h8*)&afl[l16][kk*32 + quad*8];

    f4 a0 = {b0,b0,b0,b0}, a1 = {b1,b1,b1,b1};
    #pragma unroll
    for (int kk = 0; kk < 4; ++kk) {
        a0 = __builtin_amdgcn_mfma_f32_16x16x32_f16(af[kk], wf[0][kk], a0, 0, 0, 0);
        a1 = __builtin_amdgcn_mfma_f32_16x16x32_f16(af[kk], wf[1][kk], a1, 0, 0, 0);
    }
    const int r0 = wid*16 + quad*4;
    #pragma unroll
    for (int r = 0; r < 4; ++r) {
        const int row = r0 + r;
        if (row < ROWS) {
            out[(size_t)row*DD + nt*16      + l16] = a0[r];
            out[(size_t)row*DD + nt*16 + 16 + l16] = a1[r];
        }
    }
}

extern "C" void kernel_launch(void* const* d_in, const int* in_sizes, int n_in,
                              void* d_out, int out_size, void* d_ws, size_t ws_size,
                              hipStream_t stream) {
    const float* x    = (const float*)d_in[0];
    const float* Wqkv = (const float*)d_in[1];
    const float* bqkv = (const float*)d_in[2];
    const float* Wout = (const float*)d_in[3];
    const float* bout = (const float*)d_in[4];
    for (int i = 0; i < n_in; ++i) {
        switch (in_sizes[i]) {
            case 2097664: x    = (const float*)d_in[i]; break;
            case 49152:   Wqkv = (const float*)d_in[i]; break;
            case 384:     bqkv = (const float*)d_in[i]; break;
            case 16384:   Wout = (const float*)d_in[i]; break;
            case 128:     bout = (const float*)d_in[i]; break;
            default: break;
        }
    }
    float* out = (float*)d_out;

    const size_t perh = (size_t)BH * NNP * DH;            // 2,105,344 f16
    _Float16* Qh   = (_Float16*)d_ws;                     // 4.21 MB
    _Float16* Kh   = Qh + perh;                           // 4.21 MB
    _Float16* Vt   = Kh + perh;                           // 4.21 MB
    _Float16* PACC = Vt + perh;                           // [NSP][ROWS][DD] f16 16.78 MB
    float*    PL    = (float*)(PACC + (size_t)NSP*ROWS*DD); // 2.1 MB
    _Float16* WqkvT = (_Float16*)(PL + (size_t)NSP*ROWS*HH);// 96 KB
    _Float16* WoutT = WqkvT + 384*128;                    // 32 KB -> total ~27.5 MB

    const int prep_total = 384*128 + 128*128;

    hipLaunchKernelGGL(prep, dim3((prep_total + 255)/256), dim3(256), 0, stream,
                       Wqkv, Wout, WqkvT, WoutT);
    hipLaunchKernelGGL(qkv_mfma, dim3(MT), dim3(256), 0, stream,
                       x, WqkvT, bqkv, Qh, Kh, Vt);
    hipLaunchKernelGGL(attn_mfma, dim3(17, BH, NSP), dim3(256), 0, stream,
                       Qh, Kh, Vt, PACC, PL);
    hipLaunchKernelGGL(out_mfma, dim3(MT), dim3(256), 0, stream,
                       PACC, PL, WoutT, bout, out);
}